// Round 6
// baseline (102.900 us; speedup 1.0000x reference)
//
#include <hip/hip_runtime.h>

// loss = (1/N) * sum_i || features[i] - center[labels[i]] ||_2
// N=32768, C=1000, D=512, fp32.
// R3: same-address atomics serialized (117us). R4: block partials -> 97.6us
// total, but ~65us of that is harness d_ws re-poison + d_in restore; kernel
// itself ~30us vs ~11us roofline => latency-bound (VGPR=20, ~4 loads in
// flight, 16 waves/CU). Now: 2 rows/wave fully register-staged (8 float4 in
// flight/lane), grid 4096 (32 waves/CU), nt loads for the zero-reuse
// features so the 2MB center table stays L2-resident.

typedef float f32x4 __attribute__((ext_vector_type(4)));

#define GRID  4096
#define BLOCK 256
// 16384 waves, exactly 2 rows each.

__global__ __launch_bounds__(BLOCK, 8) void intra_partial(
    const float* __restrict__ features,
    const int*   __restrict__ labels,
    const float* __restrict__ center,
    float*       __restrict__ partial)
{
    const int lane  = threadIdx.x & 63;
    const int wid   = threadIdx.x >> 6;
    const int gwave = blockIdx.x * 4 + wid;        // 0..16383

    const int r0 = gwave;
    const int r1 = gwave + 16384;

    // Labels first: the center loads depend on them.
    const int l0 = labels[r0];                     // wave-uniform
    const int l1 = labels[r1];

    // All 4 feature float4s issue immediately (independent of labels).
    // Non-temporal: features are read exactly once -> don't evict centers.
    const f32x4* f0 = (const f32x4*)(features + (size_t)r0 * 512);
    const f32x4* f1 = (const f32x4*)(features + (size_t)r1 * 512);
    const f32x4 fa0 = __builtin_nontemporal_load(f0 + lane);
    const f32x4 fb0 = __builtin_nontemporal_load(f0 + 64 + lane);
    const f32x4 fa1 = __builtin_nontemporal_load(f1 + lane);
    const f32x4 fb1 = __builtin_nontemporal_load(f1 + 64 + lane);

    // Center gathers (2MB table, L2-resident after first touch).
    const f32x4* c0 = (const f32x4*)(center + (size_t)l0 * 512);
    const f32x4* c1 = (const f32x4*)(center + (size_t)l1 * 512);
    const f32x4 ca0 = c0[lane];
    const f32x4 cb0 = c0[64 + lane];
    const f32x4 ca1 = c1[lane];
    const f32x4 cb1 = c1[64 + lane];

    f32x4 d;
    float ss0, ss1;
    d = fa0 - ca0; ss0  = d.x * d.x + d.y * d.y + d.z * d.z + d.w * d.w;
    d = fb0 - cb0; ss0 += d.x * d.x + d.y * d.y + d.z * d.z + d.w * d.w;
    d = fa1 - ca1; ss1  = d.x * d.x + d.y * d.y + d.z * d.z + d.w * d.w;
    d = fb1 - cb1; ss1 += d.x * d.x + d.y * d.y + d.z * d.z + d.w * d.w;

    // Two interleaved 64-lane shfl reduces (independent -> ILP).
    #pragma unroll
    for (int off = 32; off > 0; off >>= 1) {
        ss0 += __shfl_down(ss0, off, 64);
        ss1 += __shfl_down(ss1, off, 64);
    }

    __shared__ float s[4];
    if (lane == 0) s[wid] = sqrtf(ss0) + sqrtf(ss1);
    __syncthreads();
    if (threadIdx.x == 0)
        partial[blockIdx.x] = s[0] + s[1] + s[2] + s[3];
}

__global__ __launch_bounds__(1024) void final_reduce(
    const float* __restrict__ partial,
    float*       __restrict__ out)
{
    // GRID=4096 partials, 1024 threads: 4 each.
    float v = partial[threadIdx.x]
            + partial[threadIdx.x + 1024]
            + partial[threadIdx.x + 2048]
            + partial[threadIdx.x + 3072];

    #pragma unroll
    for (int off = 32; off > 0; off >>= 1)
        v += __shfl_down(v, off, 64);

    __shared__ float s[16];
    if ((threadIdx.x & 63) == 0) s[threadIdx.x >> 6] = v;
    __syncthreads();
    if (threadIdx.x == 0) {
        float t = 0.0f;
        #pragma unroll
        for (int i = 0; i < 16; ++i) t += s[i];
        *out = t * (1.0f / 32768.0f);              // unconditional write: no memset needed
    }
}

extern "C" void kernel_launch(void* const* d_in, const int* in_sizes, int n_in,
                              void* d_out, int out_size, void* d_ws, size_t ws_size,
                              hipStream_t stream) {
    const float* features = (const float*)d_in[0];
    const int*   labels   = (const int*)d_in[1];
    const float* center   = (const float*)d_in[2];
    float* out     = (float*)d_out;
    float* partial = (float*)d_ws;                 // 4096 floats of scratch

    intra_partial<<<GRID, BLOCK, 0, stream>>>(features, labels, center, partial);
    final_reduce<<<1, 1024, 0, stream>>>(partial, out);
}

// Round 7
// 98.055 us; speedup vs baseline: 1.0494x; 1.0494x over previous
//
#include <hip/hip_runtime.h>

// loss = (1/N) * sum_i || features[i] - center[labels[i]] ||_2
// N=32768, C=1000, D=512, fp32.
// History: R3(atomic version) 117us = same-address atomic serialization.
// R4 (block partials, grid1024): total 97.65us, kernel ~16-20us (hidden
// below the 42us ws-poison fills in top-5; harness floor ~80us).
// R6 (2 rows/wave + nontemporal): total 102.9 -> nt loads forfeited the
// L2/L3 residency created by the harness's per-replay feature restore.
// R7: no nt; grid 2048, 4 rows/wave FULLY register-staged: 4 labels issue
// first, 8 label-independent feature loads overlap them, then 8 center
// gathers; 16x16B in flight per lane. 4 interleaved reduce trees.

typedef float f32x4 __attribute__((ext_vector_type(4)));

#define GRID  2048
#define BLOCK 256
// 8192 waves, 4 rows each, rows strided by 8192.

__global__ __launch_bounds__(BLOCK) void intra_partial(
    const float* __restrict__ features,
    const int*   __restrict__ labels,
    const float* __restrict__ center,
    float*       __restrict__ partial)
{
    const int lane  = threadIdx.x & 63;
    const int wid   = threadIdx.x >> 6;
    const int gwave = blockIdx.x * 4 + wid;        // 0..8191

    const int r0 = gwave;
    const int r1 = gwave + 8192;
    const int r2 = gwave + 16384;
    const int r3 = gwave + 24576;

    // Labels first (independent, wave-uniform values).
    const int l0 = labels[r0];
    const int l1 = labels[r1];
    const int l2 = labels[r2];
    const int l3 = labels[r3];

    // 8 feature float4 loads — independent of labels, overlap their latency.
    const f32x4* f0 = (const f32x4*)(features + (size_t)r0 * 512);
    const f32x4* f1 = (const f32x4*)(features + (size_t)r1 * 512);
    const f32x4* f2 = (const f32x4*)(features + (size_t)r2 * 512);
    const f32x4* f3 = (const f32x4*)(features + (size_t)r3 * 512);
    const f32x4 fa0 = f0[lane], fb0 = f0[64 + lane];
    const f32x4 fa1 = f1[lane], fb1 = f1[64 + lane];
    const f32x4 fa2 = f2[lane], fb2 = f2[64 + lane];
    const f32x4 fa3 = f3[lane], fb3 = f3[64 + lane];

    // 8 center gathers (2MB table, L2-resident).
    const f32x4* c0 = (const f32x4*)(center + (size_t)l0 * 512);
    const f32x4* c1 = (const f32x4*)(center + (size_t)l1 * 512);
    const f32x4* c2 = (const f32x4*)(center + (size_t)l2 * 512);
    const f32x4* c3 = (const f32x4*)(center + (size_t)l3 * 512);
    const f32x4 ca0 = c0[lane], cb0 = c0[64 + lane];
    const f32x4 ca1 = c1[lane], cb1 = c1[64 + lane];
    const f32x4 ca2 = c2[lane], cb2 = c2[64 + lane];
    const f32x4 ca3 = c3[lane], cb3 = c3[64 + lane];

    f32x4 d;
    float ss0, ss1, ss2, ss3;
    d = fa0 - ca0; ss0  = d.x * d.x + d.y * d.y + d.z * d.z + d.w * d.w;
    d = fb0 - cb0; ss0 += d.x * d.x + d.y * d.y + d.z * d.z + d.w * d.w;
    d = fa1 - ca1; ss1  = d.x * d.x + d.y * d.y + d.z * d.z + d.w * d.w;
    d = fb1 - cb1; ss1 += d.x * d.x + d.y * d.y + d.z * d.z + d.w * d.w;
    d = fa2 - ca2; ss2  = d.x * d.x + d.y * d.y + d.z * d.z + d.w * d.w;
    d = fb2 - cb2; ss2 += d.x * d.x + d.y * d.y + d.z * d.z + d.w * d.w;
    d = fa3 - ca3; ss3  = d.x * d.x + d.y * d.y + d.z * d.z + d.w * d.w;
    d = fb3 - cb3; ss3 += d.x * d.x + d.y * d.y + d.z * d.z + d.w * d.w;

    // 4 interleaved 64-lane reduce trees (independent -> ILP).
    #pragma unroll
    for (int off = 32; off > 0; off >>= 1) {
        ss0 += __shfl_down(ss0, off, 64);
        ss1 += __shfl_down(ss1, off, 64);
        ss2 += __shfl_down(ss2, off, 64);
        ss3 += __shfl_down(ss3, off, 64);
    }

    __shared__ float s[4];
    if (lane == 0) s[wid] = sqrtf(ss0) + sqrtf(ss1) + sqrtf(ss2) + sqrtf(ss3);
    __syncthreads();
    if (threadIdx.x == 0)
        partial[blockIdx.x] = s[0] + s[1] + s[2] + s[3];
}

__global__ __launch_bounds__(1024) void final_reduce(
    const float* __restrict__ partial,
    float*       __restrict__ out)
{
    // GRID=2048 partials, 1024 threads: 2 each.
    float v = partial[threadIdx.x] + partial[threadIdx.x + 1024];

    #pragma unroll
    for (int off = 32; off > 0; off >>= 1)
        v += __shfl_down(v, off, 64);

    __shared__ float s[16];
    if ((threadIdx.x & 63) == 0) s[threadIdx.x >> 6] = v;
    __syncthreads();
    if (threadIdx.x == 0) {
        float t = 0.0f;
        #pragma unroll
        for (int i = 0; i < 16; ++i) t += s[i];
        *out = t * (1.0f / 32768.0f);              // unconditional write: no memset needed
    }
}

extern "C" void kernel_launch(void* const* d_in, const int* in_sizes, int n_in,
                              void* d_out, int out_size, void* d_ws, size_t ws_size,
                              hipStream_t stream) {
    const float* features = (const float*)d_in[0];
    const int*   labels   = (const int*)d_in[1];
    const float* center   = (const float*)d_in[2];
    float* out     = (float*)d_out;
    float* partial = (float*)d_ws;                 // 2048 floats of scratch

    intra_partial<<<GRID, BLOCK, 0, stream>>>(features, labels, center, partial);
    final_reduce<<<1, 1024, 0, stream>>>(partial, out);
}